// Round 13
// baseline (387.331 us; speedup 1.0000x reference)
//
#include <hip/hip_runtime.h>

// Problem constants: B=32, L=2, F=65536, D=768
#define BB 32
#define LL 2
#define FF 65536
#define DD 768
#define F4 (FF / 4)        // 16384 groups of 4 f
#define LD (LL * DD)       // 1536
#define LD2 (LD / 2)       // 768 float2
#define D2 (DD / 2)        // 384 float2 per weight row
#define BL (BB * LD)       // 49152 outputs

#define FT_FLOAT4S ((size_t)F4 * BB)            // 524288 float4 = 8.39 MB
#define FT_BYTES   (FT_FLOAT4S * sizeof(float4))
#define CHUNK_BYTES ((size_t)BL * sizeof(float))  // 196608 B
#define TMP_BYTES  ((size_t)8 * BL * sizeof(float))
#define NFMAX 512

#define FMA2(A, W, S)                                                          \
    do {                                                                       \
        (A).x = fmaf((W).x, (S), (A).x);                                       \
        (A).y = fmaf((W).y, (S), (A).y);                                       \
    } while (0)

// Explicitly wave-uniform pointer (hint for SMEM/s_load scalarization).
static __device__ __forceinline__ const float4* unif4(const float4* p)
{
    uintptr_t u = (uintptr_t)p;
    uint32_t lo = (uint32_t)__builtin_amdgcn_readfirstlane((int)(u & 0xffffffffu));
    uint32_t hi = (uint32_t)__builtin_amdgcn_readfirstlane((int)(u >> 32));
    return (const float4*)(((uintptr_t)hi << 32) | lo);
}

// Stage 0: transpose f (B x F) -> fT[g][b] as float4.
__global__ __launch_bounds__(256) void cc_transpose(
    const float4* __restrict__ f4, float4* __restrict__ fT4)
{
    size_t t = (size_t)blockIdx.x * 256 + threadIdx.x;   // 0 .. F4*32-1
    if (t >= FT_FLOAT4S) return;
    int b = (int)(t / F4);
    int g = (int)(t - (size_t)b * F4);
    fT4[(size_t)g * BB + b] = f4[t];
}

// Stage 1: partial GEMM over an F-chunk. float2 d-tile (128 d / wave),
// depth-1 weight prefetch + 4x8 ping-pong f batches, 3 waves/SIMD.
// grid = (12, NF); block = 64 (one wave).  ct: l = ct/6, dt = ct%6.
// VGPR ~155: acc 64 + w 16 + f ping-pong 64 + addr. (64,3) -> cap 170.
// partials[c][b][l*768 + dt*128 + lane*2]
__global__ __launch_bounds__(64, 3) void cc_stage1(
    const float4* __restrict__ fT4,     // [F4][32] float4
    const float* __restrict__ weight,   // L x F x D
    float* __restrict__ partials,       // NF x B x LD
    int chunk4)
{
    const int lane = threadIdx.x;
    const int ct   = blockIdx.x;        // 0..11
    const int c    = blockIdx.y;        // chunk
    const int l    = ct / 6;
    const int dt   = ct - l * 6;

    const float2* __restrict__ w2p =
        (const float2*)weight + (size_t)l * FF * D2 + (size_t)dt * 64 + lane;

    int g0 = c * chunk4;
    int g1 = g0 + chunk4;
    if (g1 > F4) g1 = F4;

    float2 acc[BB];
#pragma unroll
    for (int b = 0; b < BB; ++b) acc[b] = make_float2(0.f, 0.f);

    // current-group weight rows
    float2 wa0 = w2p[((size_t)g0 * 4 + 0) * D2];
    float2 wa1 = w2p[((size_t)g0 * 4 + 1) * D2];
    float2 wa2 = w2p[((size_t)g0 * 4 + 2) * D2];
    float2 wa3 = w2p[((size_t)g0 * 4 + 3) * D2];

    // f ping-pong batches (8 float4 each)
    float4 pA[8], pB[8];
    {
        const float4* fg = unif4(fT4 + (size_t)g0 * BB);
#pragma unroll
        for (int i = 0; i < 8; ++i) pA[i] = fg[i];
    }

    for (int g = g0; g < g1; ++g) {
        int gn = (g + 1 < g1) ? (g + 1) : g;   // clamp: last iter reloads, harmless
        // next-group weight rows (in flight across this group's FMA window)
        float2 wb0 = w2p[((size_t)gn * 4 + 0) * D2];
        float2 wb1 = w2p[((size_t)gn * 4 + 1) * D2];
        float2 wb2 = w2p[((size_t)gn * 4 + 2) * D2];
        float2 wb3 = w2p[((size_t)gn * 4 + 3) * D2];

        const float4* fg  = unif4(fT4 + (size_t)g  * BB);
        const float4* fgn = unif4(fT4 + (size_t)gn * BB);

        // pB <- b 8..15, FMA batch 0 (b 0..7) from pA
#pragma unroll
        for (int i = 0; i < 8; ++i) pB[i] = fg[8 + i];
#pragma unroll
        for (int i = 0; i < 8; ++i) {
            float4 fv = pA[i];
            FMA2(acc[i], wa0, fv.x);
            FMA2(acc[i], wa1, fv.y);
            FMA2(acc[i], wa2, fv.z);
            FMA2(acc[i], wa3, fv.w);
        }
        // pA <- b 16..23, FMA batch 1 (b 8..15) from pB
#pragma unroll
        for (int i = 0; i < 8; ++i) pA[i] = fg[16 + i];
#pragma unroll
        for (int i = 0; i < 8; ++i) {
            float4 fv = pB[i];
            FMA2(acc[8 + i], wa0, fv.x);
            FMA2(acc[8 + i], wa1, fv.y);
            FMA2(acc[8 + i], wa2, fv.z);
            FMA2(acc[8 + i], wa3, fv.w);
        }
        // pB <- b 24..31, FMA batch 2 (b 16..23) from pA
#pragma unroll
        for (int i = 0; i < 8; ++i) pB[i] = fg[24 + i];
#pragma unroll
        for (int i = 0; i < 8; ++i) {
            float4 fv = pA[i];
            FMA2(acc[16 + i], wa0, fv.x);
            FMA2(acc[16 + i], wa1, fv.y);
            FMA2(acc[16 + i], wa2, fv.z);
            FMA2(acc[16 + i], wa3, fv.w);
        }
        // pA <- NEXT group's b 0..7, FMA batch 3 (b 24..31) from pB
#pragma unroll
        for (int i = 0; i < 8; ++i) pA[i] = fgn[i];
#pragma unroll
        for (int i = 0; i < 8; ++i) {
            float4 fv = pB[i];
            FMA2(acc[24 + i], wa0, fv.x);
            FMA2(acc[24 + i], wa1, fv.y);
            FMA2(acc[24 + i], wa2, fv.z);
            FMA2(acc[24 + i], wa3, fv.w);
        }
        // rotate weight buffers
        wa0 = wb0; wa1 = wb1; wa2 = wb2; wa3 = wb3;
    }

    float2* __restrict__ out2 =
        (float2*)partials + (size_t)c * BB * LD2 + (size_t)(l * 384 + dt * 64 + lane);
#pragma unroll
    for (int b = 0; b < BB; ++b)
        out2[(size_t)b * LD2] = acc[b];
}

// Stage 2a: 8-way tree partial reduce. grid (192, 8).
// tmp[j][o] = sum_{c in j-th slice} partials[c][o]
__global__ __launch_bounds__(256) void cc_stage2a(
    const float* __restrict__ partials,
    float* __restrict__ tmp,
    int nf, int cs)
{
    int o = blockIdx.x * 256 + threadIdx.x;   // 0 .. BL-1
    if (o >= BL) return;
    int j  = blockIdx.y;                      // 0..7
    int c0 = j * cs;
    int c1 = c0 + cs;
    if (c1 > nf) c1 = nf;
    float s = 0.f;
    const float* __restrict__ p = partials + (size_t)c0 * BL + o;
#pragma unroll 16
    for (int c = c0; c < c1; ++c, p += BL)
        s += *p;
    tmp[(size_t)j * BL + o] = s;
}

// Stage 2b: out[o] = bias[ld] + sum_j tmp[j][o]
__global__ __launch_bounds__(256) void cc_stage2b(
    const float* __restrict__ tmp,
    const float* __restrict__ bias,
    float* __restrict__ out)
{
    int o = blockIdx.x * 256 + threadIdx.x;
    if (o >= BL) return;
    int b  = o / LD;
    int ld = o - b * LD;
    float s = bias[ld];
#pragma unroll
    for (int j = 0; j < 8; ++j)
        s += tmp[(size_t)j * BL + o];
    out[o] = s;
}

// Correctness-only fallback if workspace is too small.
__global__ __launch_bounds__(256) void cc_direct(
    const float* __restrict__ f,
    const float* __restrict__ weight,
    const float* __restrict__ bias,
    float* __restrict__ out)
{
    int o = blockIdx.x * 256 + threadIdx.x;
    if (o >= BL) return;
    int b  = o / LD;
    int ld = o - b * LD;
    int l  = ld / DD;
    int d  = ld - l * DD;
    float s = bias[ld];
    const float* wp = weight + (size_t)l * FF * DD + d;
    const float* fp = f + (size_t)b * FF;
    for (int fi = 0; fi < FF; ++fi)
        s = fmaf(fp[fi], wp[(size_t)fi * DD], s);
    out[o] = s;
}

extern "C" void kernel_launch(void* const* d_in, const int* in_sizes, int n_in,
                              void* d_out, int out_size, void* d_ws, size_t ws_size,
                              hipStream_t stream)
{
    const float* f      = (const float*)d_in[0];   // 32 x 65536
    const float* weight = (const float*)d_in[1];   // 2 x 65536 x 768
    const float* bias   = (const float*)d_in[2];   // 2 x 768
    float* out          = (float*)d_out;           // 32 x 2 x 768

    if (ws_size < FT_BYTES + TMP_BYTES + CHUNK_BYTES) {
        cc_direct<<<(BL + 255) / 256, 256, 0, stream>>>(f, weight, bias, out);
        return;
    }

    int nf = (int)((ws_size - FT_BYTES - TMP_BYTES) / CHUNK_BYTES);
    if (nf > NFMAX) nf = NFMAX;
    int chunk4 = (F4 + nf - 1) / nf;        // 32 when nf=512
    nf = (F4 + chunk4 - 1) / chunk4;

    float4* fT4      = (float4*)d_ws;
    float*  partials = (float*)((char*)d_ws + FT_BYTES);
    float*  tmp      = (float*)((char*)d_ws + FT_BYTES + (size_t)nf * CHUNK_BYTES);

    cc_transpose<<<(int)((FT_FLOAT4S + 255) / 256), 256, 0, stream>>>(
        (const float4*)f, fT4);

    dim3 grid1(12, nf);
    cc_stage1<<<grid1, 64, 0, stream>>>(fT4, weight, partials, chunk4);

    int cs = (nf + 7) / 8;
    dim3 grid2a((BL + 255) / 256, 8);
    cc_stage2a<<<grid2a, 256, 0, stream>>>(partials, tmp, nf, cs);
    cc_stage2b<<<(BL + 255) / 256, 256, 0, stream>>>(tmp, bias, out);
}